// Round 10
// baseline (117.558 us; speedup 1.0000x reference)
//
#include <hip/hip_runtime.h>

#define LOG2E 1.4426950408889634f

constexpr int Bsz = 4096, Ssz = 128, Isz = 64, MOTOR = 32;
constexpr int BT = 2, NT = 128, R = 2;   // 128 thr = one per s; 2 rows/thread; 2-wave blocks

// ---- prep: fold constants, pack T[quad][{a,b,w}][s] as float4 ----
// a = -sigma*log2e ; b = sigma*mu*log2e ; w = w*mask*erev (sign carries erev)
__global__ void ltc_prep(const float* __restrict__ w, const float* __restrict__ sigma,
                         const float* __restrict__ mu, const float* __restrict__ erev,
                         const float* __restrict__ smask,
                         const float* __restrict__ sw, const float* __restrict__ ssig,
                         const float* __restrict__ smu, const float* __restrict__ serev,
                         const float* __restrict__ ssmask,
                         float4* __restrict__ Tm, float4* __restrict__ Ts)
{
  int idx = blockIdx.x * blockDim.x + threadIdx.x;
  if (idx < 32 * Ssz) {                    // main: 32 j-quads x 128 s
    int q = idx >> 7, s = idx & 127;
    float4 a, b, wv;
    #pragma unroll
    for (int jj = 0; jj < 4; ++jj) {
      int e = (q * 4 + jj) * Ssz + s;
      float sg = sigma[e];
      (&a.x)[jj] = -sg * LOG2E;
      (&b.x)[jj] = sg * mu[e] * LOG2E;
      (&wv.x)[jj] = w[e] * smask[e] * erev[e];
    }
    Tm[(q * 3 + 0) * Ssz + s] = a;
    Tm[(q * 3 + 1) * Ssz + s] = b;
    Tm[(q * 3 + 2) * Ssz + s] = wv;
  } else if (idx < 32 * Ssz + 16 * Ssz) {  // sensory: 16 i-quads x 128 s
    int k = idx - 32 * Ssz;
    int q = k >> 7, s = k & 127;
    float4 a, b, wv;
    #pragma unroll
    for (int jj = 0; jj < 4; ++jj) {
      int e = (q * 4 + jj) * Ssz + s;
      float sg = ssig[e];
      (&a.x)[jj] = -sg * LOG2E;
      (&b.x)[jj] = sg * smu[e] * LOG2E;
      (&wv.x)[jj] = sw[e] * ssmask[e] * serev[e];
    }
    Ts[(q * 3 + 0) * Ssz + s] = a;
    Ts[(q * 3 + 1) * Ssz + s] = b;
    Ts[(q * 3 + 2) * Ssz + s] = wv;
  }
}

__launch_bounds__(NT, 4)   // cap 128 VGPR; live set ~40, no spill
__global__ void ltc_main(const float* __restrict__ inputs, const float* __restrict__ states,
                         const float* __restrict__ gleak, const float* __restrict__ vleak,
                         const float* __restrict__ cmv,
                         const float* __restrict__ iw, const float* __restrict__ ib,
                         const float* __restrict__ ow, const float* __restrict__ ob,
                         const float4* __restrict__ Tm, const float4* __restrict__ Ts,
                         float* __restrict__ out)
{
  __shared__ float vsh[2][BT][Ssz];   // double-buffered state: 2 KB
  __shared__ float xsh[BT][Isz];      // 0.5 KB

  const int t = threadIdx.x;
  const int s = t;                    // one thread per state column
  const int b0 = blockIdx.x * BT;

  // stage x = inputs*iw + ib and v = states into LDS
  { int r = t >> 6, i = t & 63;       // 128 threads = 2 rows x 64 inputs exactly
    xsh[r][i] = inputs[(b0 + r) * Isz + i] * iw[i] + ib[i]; }
  #pragma unroll
  for (int k = 0; k < BT; ++k)
    vsh[0][k][s] = states[(b0 + k) * Ssz + s];
  const float cmt = cmv[s] * 6.0f;    // cm / (1.0/6)
  const float gl = gleak[s];
  const float gv = gl * vleak[s];
  const float dbase = cmt + gl + 1e-8f;
  __syncthreads();

  // ---- sensory sums: full i-range (16 quads), this thread's R rows ----
  float sn[R] = {0.f, 0.f}, sd[R] = {0.f, 0.f};
  {
    const float4* pb = Ts + 1 * Ssz + s;       // points at b of quad 0
    #pragma unroll 2
    for (int q = 0; q < 16; ++q) {
      float4 a4 = pb[-Ssz], b4 = pb[0], w4 = pb[Ssz];
      pb += 3 * Ssz;
      #pragma unroll
      for (int r = 0; r < R; ++r) {
        float4 xq = *(const float4*)&xsh[r][q * 4];   // broadcast read
        #pragma unroll
        for (int jj = 0; jj < 4; ++jj) {
          float arg = fmaf((&a4.x)[jj], (&xq.x)[jj], (&b4.x)[jj]);
          float u = __builtin_amdgcn_exp2f(arg);
          float sig = __builtin_amdgcn_rcpf(1.0f + u);
          sn[r] = fmaf((&w4.x)[jj], sig, sn[r]);
          sd[r] = fmaf(fabsf((&w4.x)[jj]), sig, sd[r]);
        }
      }
    }
  }

  // ---- 6 ODE unfolds: full j-sum per thread, 1 barrier per unfold ----
  #pragma unroll 1
  for (int it = 0; it < 6; ++it) {
    const int cur = it & 1;
    const float* vcur = &vsh[cur][0][0];
    float num[R], den[R];
    #pragma unroll
    for (int r = 0; r < R; ++r) { num[r] = sn[r]; den[r] = sd[r]; }

    const float4* pb = Tm + 1 * Ssz + s;       // b of quad 0
    #pragma unroll 2
    for (int q = 0; q < 32; ++q) {
      float4 a4 = pb[-Ssz], b4 = pb[0], w4 = pb[Ssz];
      pb += 3 * Ssz;
      #pragma unroll
      for (int r = 0; r < R; ++r) {
        float4 vq = *(const float4*)&vcur[r * Ssz + q * 4];  // broadcast read
        #pragma unroll
        for (int jj = 0; jj < 4; ++jj) {
          float arg = fmaf((&a4.x)[jj], (&vq.x)[jj], (&b4.x)[jj]);
          float u = __builtin_amdgcn_exp2f(arg);
          float sig = __builtin_amdgcn_rcpf(1.0f + u);
          num[r] = fmaf((&w4.x)[jj], sig, num[r]);
          den[r] = fmaf(fabsf((&w4.x)[jj]), sig, den[r]);
        }
      }
    }

    #pragma unroll
    for (int r = 0; r < R; ++r) {
      float vo = vcur[r * Ssz + s];
      vsh[cur ^ 1][r][s] =
          (fmaf(cmt, vo, gv) + num[r]) * __builtin_amdgcn_rcpf(dbase + den[r]);
    }
    __syncthreads();   // new buffer fully written & visible before next unfold reads it
  }

  // final state lives in vsh[0] (it=5 writes buffer 0)
  // ---- outputs: [B*32] motor affine, then [B*128] v_pre ----
  #pragma unroll
  for (int k = 0; k < BT; ++k)
    out[Bsz * MOTOR + (b0 + k) * Ssz + s] = vsh[0][k][s];
  { int r = t >> 5, m = t & 31;       // 128 threads = 2 rows x 32 motors... (r<BT*? )
    if (r < BT * 2) {                 // 128 threads cover 4 row-slots; only BT=2 valid
      if (r < BT)
        out[(b0 + r) * MOTOR + m] = fmaf(vsh[0][r][m], ow[m], ob[m]);
    }
  }
}

extern "C" void kernel_launch(void* const* d_in, const int* in_sizes, int n_in,
                              void* d_out, int out_size, void* d_ws, size_t ws_size,
                              hipStream_t stream) {
  const float* inputs = (const float*)d_in[0];
  const float* states = (const float*)d_in[1];
  const float* gleak  = (const float*)d_in[2];
  const float* vleak  = (const float*)d_in[3];
  const float* cmv    = (const float*)d_in[4];
  const float* w      = (const float*)d_in[5];
  const float* sigma  = (const float*)d_in[6];
  const float* mu     = (const float*)d_in[7];
  const float* erev   = (const float*)d_in[8];
  const float* sw     = (const float*)d_in[9];
  const float* ssig   = (const float*)d_in[10];
  const float* smu    = (const float*)d_in[11];
  const float* serev  = (const float*)d_in[12];
  const float* smask  = (const float*)d_in[13];
  const float* ssmask = (const float*)d_in[14];
  const float* iw     = (const float*)d_in[15];
  const float* ib     = (const float*)d_in[16];
  const float* ow     = (const float*)d_in[17];
  const float* ob     = (const float*)d_in[18];

  char* ws = (char*)d_ws;
  float4* Tm = (float4*)ws;                  // 32 quads * 3 * 128 * 16B = 196608
  float4* Ts = (float4*)(ws + 196608);       // 16 quads * 3 * 128 * 16B =  98304
  float* out = (float*)d_out;

  constexpr int prep_items = 32 * Ssz + 16 * Ssz;   // 6144
  ltc_prep<<<(prep_items + 255) / 256, 256, 0, stream>>>(
      w, sigma, mu, erev, smask, sw, ssig, smu, serev, ssmask, Tm, Ts);
  ltc_main<<<Bsz / BT, NT, 0, stream>>>(
      inputs, states, gleak, vleak, cmv, iw, ib, ow, ob, Tm, Ts, out);
}

// Round 11
// 113.932 us; speedup vs baseline: 1.0318x; 1.0318x over previous
//
#include <hip/hip_runtime.h>

#define LOG2E 1.4426950408889634f

constexpr int Bsz = 4096, Ssz = 128, Isz = 64, MOTOR = 32;
constexpr int BT = 2, NT = 64;   // single-wave blocks; lane owns cols t and t+64, BT rows

// ---- prep: fold constants, pack T[quad][{a,b,w}][s] as float4 ----
// a = -sigma*log2e ; b = sigma*mu*log2e ; w = w*mask*erev (sign carries erev)
__global__ void ltc_prep(const float* __restrict__ w, const float* __restrict__ sigma,
                         const float* __restrict__ mu, const float* __restrict__ erev,
                         const float* __restrict__ smask,
                         const float* __restrict__ sw, const float* __restrict__ ssig,
                         const float* __restrict__ smu, const float* __restrict__ serev,
                         const float* __restrict__ ssmask,
                         float4* __restrict__ Tm, float4* __restrict__ Ts)
{
  int idx = blockIdx.x * blockDim.x + threadIdx.x;
  if (idx < 32 * Ssz) {                    // main: 32 j-quads x 128 s
    int q = idx >> 7, s = idx & 127;
    float4 a, b, wv;
    #pragma unroll
    for (int jj = 0; jj < 4; ++jj) {
      int e = (q * 4 + jj) * Ssz + s;
      float sg = sigma[e];
      (&a.x)[jj] = -sg * LOG2E;
      (&b.x)[jj] = sg * mu[e] * LOG2E;
      (&wv.x)[jj] = w[e] * smask[e] * erev[e];
    }
    Tm[(q * 3 + 0) * Ssz + s] = a;
    Tm[(q * 3 + 1) * Ssz + s] = b;
    Tm[(q * 3 + 2) * Ssz + s] = wv;
  } else if (idx < 32 * Ssz + 16 * Ssz) {  // sensory: 16 i-quads x 128 s
    int k = idx - 32 * Ssz;
    int q = k >> 7, s = k & 127;
    float4 a, b, wv;
    #pragma unroll
    for (int jj = 0; jj < 4; ++jj) {
      int e = (q * 4 + jj) * Ssz + s;
      float sg = ssig[e];
      (&a.x)[jj] = -sg * LOG2E;
      (&b.x)[jj] = sg * smu[e] * LOG2E;
      (&wv.x)[jj] = sw[e] * ssmask[e] * serev[e];
    }
    Ts[(q * 3 + 0) * Ssz + s] = a;
    Ts[(q * 3 + 1) * Ssz + s] = b;
    Ts[(q * 3 + 2) * Ssz + s] = wv;
  }
}

__launch_bounds__(NT, 2)   // generous VGPR cap; residency is grid-limited anyway
__global__ void ltc_main(const float* __restrict__ inputs, const float* __restrict__ states,
                         const float* __restrict__ gleak, const float* __restrict__ vleak,
                         const float* __restrict__ cmv,
                         const float* __restrict__ iw, const float* __restrict__ ib,
                         const float* __restrict__ ow, const float* __restrict__ ob,
                         const float4* __restrict__ Tm, const float4* __restrict__ Ts,
                         float* __restrict__ out)
{
  __shared__ float vsh[BT][Ssz];      // 1 KB, single-buffered (single wave = in-order)
  __shared__ float xsh[BT][Isz];      // 0.5 KB

  const int t = threadIdx.x;          // 0..63
  const int s0 = t, s1 = t + 64;
  const int b0 = blockIdx.x * BT;

  // stage x = inputs*iw + ib (2 values per lane)
  #pragma unroll
  for (int k = t; k < BT * Isz; k += NT) {
    int r = k >> 6, i = k & 63;
    xsh[r][i] = inputs[(b0 + r) * Isz + i] * iw[i] + ib[i];
  }
  // state in registers + LDS copy for cross-lane broadcast
  float vr0[BT], vr1[BT];
  #pragma unroll
  for (int r = 0; r < BT; ++r) {
    vr0[r] = states[(b0 + r) * Ssz + s0];
    vr1[r] = states[(b0 + r) * Ssz + s1];
    vsh[r][s0] = vr0[r];
    vsh[r][s1] = vr1[r];
  }
  const float cmt0 = cmv[s0] * 6.0f, cmt1 = cmv[s1] * 6.0f;   // cm / (1.0/6)
  const float gl0 = gleak[s0], gl1 = gleak[s1];
  const float gv0 = gl0 * vleak[s0], gv1 = gl1 * vleak[s1];
  const float db0 = cmt0 + gl0 + 1e-8f, db1 = cmt1 + gl1 + 1e-8f;
  // no __syncthreads anywhere: single wave, lockstep + compiler lgkmcnt

  // ---- sensory sums: 16 i-quads, 2 cols x BT rows per lane ----
  float sn0[BT] = {0.f, 0.f}, sd0[BT] = {0.f, 0.f};
  float sn1[BT] = {0.f, 0.f}, sd1[BT] = {0.f, 0.f};
  {
    const float4* pb = Ts + 1 * Ssz + s0;       // b-plane of quad 0, col s0
    #pragma unroll 2
    for (int q = 0; q < 16; ++q) {
      float4 aA = pb[-Ssz], aB = pb[-Ssz + 64];
      float4 bA = pb[0],    bB = pb[64];
      float4 wA = pb[Ssz],  wB = pb[Ssz + 64];
      pb += 3 * Ssz;
      #pragma unroll
      for (int r = 0; r < BT; ++r) {
        float4 xq = *(const float4*)&xsh[r][q * 4];   // broadcast read (row-shared)
        #pragma unroll
        for (int jj = 0; jj < 4; ++jj) {
          float x = (&xq.x)[jj];
          { float arg = fmaf((&aA.x)[jj], x, (&bA.x)[jj]);
            float u = __builtin_amdgcn_exp2f(arg);
            float sig = __builtin_amdgcn_rcpf(1.0f + u);
            sn0[r] = fmaf((&wA.x)[jj], sig, sn0[r]);
            sd0[r] = fmaf(fabsf((&wA.x)[jj]), sig, sd0[r]); }
          { float arg = fmaf((&aB.x)[jj], x, (&bB.x)[jj]);
            float u = __builtin_amdgcn_exp2f(arg);
            float sig = __builtin_amdgcn_rcpf(1.0f + u);
            sn1[r] = fmaf((&wB.x)[jj], sig, sn1[r]);
            sd1[r] = fmaf(fabsf((&wB.x)[jj]), sig, sd1[r]); }
        }
      }
    }
  }

  // ---- 6 ODE unfolds: full j-sum per lane for 2 cols, zero barriers ----
  #pragma unroll 1
  for (int it = 0; it < 6; ++it) {
    float n0[BT], d0[BT], n1[BT], d1[BT];
    #pragma unroll
    for (int r = 0; r < BT; ++r) {
      n0[r] = sn0[r]; d0[r] = sd0[r];
      n1[r] = sn1[r]; d1[r] = sd1[r];
    }

    const float4* pq = Tm + 1 * Ssz + s0;       // b-plane of quad 0, col s0
    #pragma unroll 2
    for (int q = 0; q < 32; ++q) {
      float4 aA = pq[-Ssz], aB = pq[-Ssz + 64];
      float4 bA = pq[0],    bB = pq[64];
      float4 wA = pq[Ssz],  wB = pq[Ssz + 64];
      pq += 3 * Ssz;
      #pragma unroll
      for (int r = 0; r < BT; ++r) {
        float4 vq = *(const float4*)&vsh[r][q * 4];   // broadcast read (row-shared)
        #pragma unroll
        for (int jj = 0; jj < 4; ++jj) {
          float v = (&vq.x)[jj];
          { float arg = fmaf((&aA.x)[jj], v, (&bA.x)[jj]);
            float u = __builtin_amdgcn_exp2f(arg);
            float sig = __builtin_amdgcn_rcpf(1.0f + u);
            n0[r] = fmaf((&wA.x)[jj], sig, n0[r]);
            d0[r] = fmaf(fabsf((&wA.x)[jj]), sig, d0[r]); }
          { float arg = fmaf((&aB.x)[jj], v, (&bB.x)[jj]);
            float u = __builtin_amdgcn_exp2f(arg);
            float sig = __builtin_amdgcn_rcpf(1.0f + u);
            n1[r] = fmaf((&wB.x)[jj], sig, n1[r]);
            d1[r] = fmaf(fabsf((&wB.x)[jj]), sig, d1[r]); }
        }
      }
    }

    // update state: all j-loop reads are complete (wave lockstep) -> safe in-place
    #pragma unroll
    for (int r = 0; r < BT; ++r) {
      float u0 = (fmaf(cmt0, vr0[r], gv0) + n0[r]) * __builtin_amdgcn_rcpf(db0 + d0[r]);
      float u1 = (fmaf(cmt1, vr1[r], gv1) + n1[r]) * __builtin_amdgcn_rcpf(db1 + d1[r]);
      vr0[r] = u0; vr1[r] = u1;
      vsh[r][s0] = u0; vsh[r][s1] = u1;
    }
  }

  // ---- outputs: [B*32] motor affine, then [B*128] v_pre ----
  #pragma unroll
  for (int r = 0; r < BT; ++r) {
    out[Bsz * MOTOR + (b0 + r) * Ssz + s0] = vr0[r];
    out[Bsz * MOTOR + (b0 + r) * Ssz + s1] = vr1[r];
  }
  if (t < MOTOR) {
    float owm = ow[t], obm = ob[t];
    #pragma unroll
    for (int r = 0; r < BT; ++r)
      out[(b0 + r) * MOTOR + t] = fmaf(vr0[r], owm, obm);
  }
}

extern "C" void kernel_launch(void* const* d_in, const int* in_sizes, int n_in,
                              void* d_out, int out_size, void* d_ws, size_t ws_size,
                              hipStream_t stream) {
  const float* inputs = (const float*)d_in[0];
  const float* states = (const float*)d_in[1];
  const float* gleak  = (const float*)d_in[2];
  const float* vleak  = (const float*)d_in[3];
  const float* cmv    = (const float*)d_in[4];
  const float* w      = (const float*)d_in[5];
  const float* sigma  = (const float*)d_in[6];
  const float* mu     = (const float*)d_in[7];
  const float* erev   = (const float*)d_in[8];
  const float* sw     = (const float*)d_in[9];
  const float* ssig   = (const float*)d_in[10];
  const float* smu    = (const float*)d_in[11];
  const float* serev  = (const float*)d_in[12];
  const float* smask  = (const float*)d_in[13];
  const float* ssmask = (const float*)d_in[14];
  const float* iw     = (const float*)d_in[15];
  const float* ib     = (const float*)d_in[16];
  const float* ow     = (const float*)d_in[17];
  const float* ob     = (const float*)d_in[18];

  char* ws = (char*)d_ws;
  float4* Tm = (float4*)ws;                  // 32 quads * 3 * 128 * 16B = 196608
  float4* Ts = (float4*)(ws + 196608);       // 16 quads * 3 * 128 * 16B =  98304
  float* out = (float*)d_out;

  constexpr int prep_items = 32 * Ssz + 16 * Ssz;   // 6144
  ltc_prep<<<(prep_items + 255) / 256, 256, 0, stream>>>(
      w, sigma, mu, erev, smask, sw, ssig, smu, serev, ssmask, Tm, Ts);
  ltc_main<<<Bsz / BT, NT, 0, stream>>>(
      inputs, states, gleak, vleak, cmv, iw, ib, ow, ob, Tm, Ts, out);
}